// Round 14
// baseline (380.031 us; speedup 1.0000x reference)
//
#include <hip/hip_runtime.h>

#define GRID 64
#define TPB 512
#define SLICE 64          // memory rows per block
#define BB 4
#define DD 256
#define NN 1024
#define MM 256
#define KSH 3
#define RPL 265   // M+K+6
#define WPL 775   // 3M+K+4
#define TS 32
#define EPSF 1e-12f

struct KArgs {
    const float *ctrl, *rW, *rb, *wW, *wb;
    const float *memory0, *prec0, *read_w0, *write_w0;
    float *out;
    float *rp, *wp;                        // params: cached (published once via fenced barrier)
    float *cosr, *cosw, *wbuf, *rdw;       // [2][B][N] parity double-buffered, LLC-coherent access
    float *csp, *dsp;                      // [2][GRID][TS]
    float *rdp;                            // [2][GRID][MM] coalesced
    unsigned *flagsA, *flagsB;
};

// LLC-coherent scalar access (sc0 sc1): bypasses non-coherent L1/L2, no fences needed.
__device__ __forceinline__ float cload(const float* p){
    return __hip_atomic_load(p, __ATOMIC_RELAXED, __HIP_MEMORY_SCOPE_SYSTEM);
}
__device__ __forceinline__ void cstore(float* p, float v){
    __hip_atomic_store(p, v, __ATOMIC_RELAXED, __HIP_MEMORY_SCOPE_SYSTEM);
}

__device__ __forceinline__ float softplusf(float x){
    return fmaxf(x, 0.0f) + log1pf(expf(-fabsf(x)));
}
__device__ __forceinline__ float sigmoidf(float x){
    return 1.0f / (1.0f + expf(-x));
}

// decentralized split-phase barrier; 64 flags -> 1 flag per lane in wave 0.
template <bool FENCE>
__device__ __forceinline__ void garrive(unsigned* flags, unsigned gen, int g, int tid){
    __syncthreads();
    if (tid == 0){
        if (FENCE) __builtin_amdgcn_fence(__ATOMIC_RELEASE, "agent");
        __hip_atomic_store(&flags[g*16], gen, __ATOMIC_RELAXED, __HIP_MEMORY_SCOPE_SYSTEM);
    }
}
template <bool FENCE>
__device__ __forceinline__ void gwait(unsigned* flags, unsigned gen, int tid){
    if (tid < 64){
        while (1){
            unsigned f0 = __hip_atomic_load(&flags[tid*16], __ATOMIC_RELAXED, __HIP_MEMORY_SCOPE_SYSTEM);
            if (__all(f0 >= gen)) break;
            __builtin_amdgcn_s_sleep(1);
        }
    }
    __syncthreads();
    if (FENCE) __builtin_amdgcn_fence(__ATOMIC_ACQUIRE, "agent");
    asm volatile("" ::: "memory");
}

// single-sync 256-thread team sum; caller provides a DISTINCT 4-slot buffer.
__device__ __forceinline__ float team_sum(float v, float* slot4, int ttid){
    #pragma unroll
    for (int off = 32; off; off >>= 1) v += __shfl_down(v, off);
    if ((ttid & 63) == 0) slot4[ttid >> 6] = v;
    __syncthreads();
    return slot4[0] + slot4[1] + slot4[2] + slot4[3];
}

// 256-thread team addressing: 4 elems/thread over N=1024, 3 block syncs.
// Both teams execute identical call sites (same __syncthreads count).
__device__ __forceinline__ void addr_team(const float cosx[4], const float prev[4],
                                          const float* __restrict__ p,
                                          float* swg, float* slot_bs, float* slot_ts,
                                          int ttid, float out_wc[4]){
    float beta_p  = softplusf(p[MM]);
    float g       = sigmoidf(p[MM+1]);
    float s0r = p[MM+2], s1r = p[MM+3], s2r = p[MM+4];
    float smx = fmaxf(s0r, fmaxf(s1r, s2r));
    float e0 = expf(s0r-smx), e1 = expf(s1r-smx), e2 = expf(s2r-smx);
    float sden = e0+e1+e2;
    float s0 = e0/sden, s1 = e1/sden, s2 = e2/sden;
    float gamma_p = 1.0f + softplusf(p[MM+2+KSH]);
    // bmax := beta_p (>= max beta_p*cos, shift-invariant, no reduction needed)
    float ev[4]; float ls = 0.0f;
    #pragma unroll
    for (int q = 0; q < 4; q++){ ev[q] = expf(beta_p*cosx[q] - beta_p); ls += ev[q]; }
    float bs = team_sum(ls, slot_bs, ttid);             // sync 1
    float invb = 1.0f / bs;
    #pragma unroll
    for (int q = 0; q < 4; q++){
        int i = ttid + q*256;
        swg[i] = g*(ev[q]*invb) + (1.0f-g)*prev[q];
    }
    __syncthreads();                                    // sync 2
    float wt[4]; float lps = 0.0f;
    #pragma unroll
    for (int q = 0; q < 4; q++){
        int i = ttid + q*256;
        float sh = s0*swg[(i+1)&(NN-1)] + s1*swg[i] + s2*swg[(i-1)&(NN-1)];
        wt[q] = exp2f(gamma_p * log2f(sh + EPSF));
        lps += wt[q];
    }
    float ts2 = team_sum(lps, slot_ts, ttid);           // sync 3
    float inv = 1.0f / (ts2 + EPSF);
    #pragma unroll
    for (int q = 0; q < 4; q++) out_wc[q] = wt[q] * inv;
    // no trailing sync: next block-wide sync protects swg reuse
}

// Tail part 1 for step tnext: fused {reads_{tnext-1} partial + mem update}
// (thread = (col, row-half)), wave-fragment reduce in wred, ONE coalesced rdp
// cstore, then 8-lane-group cos dot + publishes.
__device__ __forceinline__ void tail_cos(const KArgs& a, int tnext, int b, int g, int ns0,
        float (*lmem)[MM], float (*skey)[MM], float* wred,
        const float* lwn, const float* rdvec, int tid){
    const float* kr = a.rp + (size_t)tnext*BB*RPL + (size_t)b*RPL;
    const bool hw = (tnext+1 <= TS-1);
    const float* kwp = a.wp + (size_t)(hw ? tnext+1 : tnext)*BB*WPL + (size_t)b*WPL;
    if (tid < 256) skey[0][tid] = kr[tid];
    else           skey[1][tid-256] = kwp[tid-256];
    __syncthreads();   // skey staged; caller's lrn/lwn publishes visible
    {
        const int col = tid & 255, rg = tid >> 8;
        const float* pw = a.wp + (size_t)tnext*BB*WPL + (size_t)b*WPL;
        float e = pw[MM+3+KSH + col];       // pre-sigmoided erase
        float d = pw[2*MM+3+KSH + col];
        float accv = 0.f;
        #pragma unroll 8
        for (int k = 0; k < 32; k++){
            int j = rg*32 + k;
            float w = lwn[j];
            float mv = lmem[j][col];
            if (rdvec) accv += rdvec[j]*mv;
            lmem[j][col] = mv*(1.0f - w*e) + w*d;
        }
        if (rdvec) wred[rg*256 + col] = accv;
    }
    __syncthreads();
    if (rdvec && tid < 256)
        cstore(&a.rdp[(size_t)((tnext-1)&1)*GRID*MM + g*MM + tid], wred[tid] + wred[256+tid]);
    {
        int j = tid >> 3, c = tid & 7;     // 64 rows x 8 lanes
        float dr=0.f, dw=0.f, nm=0.f, nr=0.f, nk=0.f;
        #pragma unroll
        for (int m = 0; m < 8; m++){
            int col = c*4 + m*32;
            float4 mv = *(const float4*)&lmem[j][col];
            float4 rv = *(const float4*)&skey[0][col];
            float4 wv = *(const float4*)&skey[1][col];
            dr += mv.x*rv.x + mv.y*rv.y + mv.z*rv.z + mv.w*rv.w;
            dw += mv.x*wv.x + mv.y*wv.y + mv.z*wv.z + mv.w*wv.w;
            nm += mv.x*mv.x + mv.y*mv.y + mv.z*mv.z + mv.w*mv.w;
            nr += rv.x*rv.x + rv.y*rv.y + rv.z*rv.z + rv.w*rv.w;
            nk += wv.x*wv.x + wv.y*wv.y + wv.z*wv.z + wv.w*wv.w;
        }
        #pragma unroll
        for (int off = 4; off; off >>= 1){
            dr += __shfl_down(dr, off); dw += __shfl_down(dw, off);
            nm += __shfl_down(nm, off); nr += __shfl_down(nr, off);
            nk += __shfl_down(nk, off);
        }
        if (c == 0){
            float sn = sqrtf(nm) + EPSF;
            int n = ns0 + j;
            cstore(&a.cosr[(size_t)(tnext&1)*BB*NN + b*NN + n], dr/(sn*(sqrtf(nr)+EPSF)));
            if (hw) cstore(&a.cosw[(size_t)((tnext+1)&1)*BB*NN + b*NN + n], dw/(sn*(sqrtf(nk)+EPSF)));
        }
    }
}

// Tail part 2: A/W scale+append + cs/ds partials (8 lanes x 8 elems over 64 rows).
__device__ __forceinline__ void tail_links(const KArgs& a, int tnext, int g,
        float (*lA)[SLICE], float (*lW)[SLICE],
        const float* lwn, const float* rvec, const float* lprec, int tid){
    for (int p2 = tid; p2 < tnext*SLICE; p2 += TPB){
        int s = p2 >> 6, jj = p2 & 63;
        lA[s][jj] *= (1.0f - lwn[jj]);
    }
    __syncthreads();
    if (tid < SLICE){ lA[tnext][tid] = lprec[tid]; lW[tnext][tid] = lwn[tid]; }
    __syncthreads();
    int s = tid >> 3, c = tid & 7;
    if (s <= tnext){
        float pc = 0.f, pd = 0.f;
        #pragma unroll
        for (int q = 0; q < 8; q++){
            int jj = c*8 + q;
            float r = rvec[jj];
            pc += r*lA[s][jj];
            pd += r*lW[s][jj];
        }
        #pragma unroll
        for (int off = 4; off; off >>= 1){ pc += __shfl_down(pc, off); pd += __shfl_down(pd, off); }
        if (c == 0){
            cstore(&a.csp[(size_t)(tnext&1)*GRID*TS + g*TS + s], pc);
            cstore(&a.dsp[(size_t)(tnext&1)*GRID*TS + g*TS + s], pd);
        }
    }
}

__global__ void __launch_bounds__(TPB) kfull(KArgs a){
    const int g   = blockIdx.x;
    const int tid = threadIdx.x;
    const int wvi = tid >> 6, lane = tid & 63;
    const int b   = g >> 4;             // batch (4 batches x 16 slices)
    const int sl  = g & 15;             // slice index within batch
    const int ns0 = sl * SLICE;         // first row of slice
    const int qsl   = ns0 >> 8;         // team layout: slice q (4 elems/thread)
    const int hbase = ns0 & 255;        // team layout: slice ttid base

    __shared__ __align__(16) float lmem[SLICE][MM];   // 64 KB memory slice
    __shared__ __align__(16) float skey[2][MM];
    __shared__ __align__(16) float lA[TS][SLICE];     // 8 KB
    __shared__ __align__(16) float lW[TS][SLICE];     // 8 KB
    __shared__ __align__(16) float wgA[NN], wgB[NN];  // team swg / wred scratch
    __shared__ float s16[16];
    __shared__ float scs[TS], sds[TS];
    __shared__ float lprec[SLICE], lr_old[SLICE], lw_old[SLICE];
    __shared__ float lrn[SLICE], lwn[SLICE], lbw[SLICE], lfw[SLICE];

    // ===== Phase A: projections (2 blocks per t; cached stores; fenced publish) =====
    {
        const int tt = g >> 1, hp = g & 1;
        for (int o = tid; o < BB*DD; o += TPB) wgA[o] = a.ctrl[(size_t)tt*BB*DD + o];
        __syncthreads();
        for (int jo = tid; jo < 520; jo += TPB){
            int j = hp*520 + jo;
            if (j < RPL + WPL){
                const float* wrow; float bias; int isw, jj;
                if (j < RPL){ jj = j;       wrow = a.rW + (size_t)jj*DD; bias = a.rb[jj]; isw = 0; }
                else        { jj = j - RPL; wrow = a.wW + (size_t)jj*DD; bias = a.wb[jj]; isw = 1; }
                const float4* w4 = (const float4*)wrow;
                float a0 = bias, a1 = bias, a2 = bias, a3 = bias;
                for (int d = 0; d < DD/4; d++){
                    float4 wv = w4[d];
                    float4 c0 = *(const float4*)&wgA[0*DD + d*4];
                    float4 c1 = *(const float4*)&wgA[1*DD + d*4];
                    float4 c2 = *(const float4*)&wgA[2*DD + d*4];
                    float4 c3 = *(const float4*)&wgA[3*DD + d*4];
                    a0 += wv.x*c0.x + wv.y*c0.y + wv.z*c0.z + wv.w*c0.w;
                    a1 += wv.x*c1.x + wv.y*c1.y + wv.z*c1.z + wv.w*c1.w;
                    a2 += wv.x*c2.x + wv.y*c2.y + wv.z*c2.z + wv.w*c2.w;
                    a3 += wv.x*c3.x + wv.y*c3.y + wv.z*c3.z + wv.w*c3.w;
                }
                if (isw && jj >= MM+3+KSH && jj < 2*MM+3+KSH){  // erase -> sigmoid once
                    a0 = sigmoidf(a0); a1 = sigmoidf(a1); a2 = sigmoidf(a2); a3 = sigmoidf(a3);
                }
                if (!isw){
                    float* dst = a.rp + (size_t)tt*BB*RPL;
                    dst[0*RPL+jj]=a0; dst[1*RPL+jj]=a1; dst[2*RPL+jj]=a2; dst[3*RPL+jj]=a3;
                } else {
                    float* dst = a.wp + (size_t)tt*BB*WPL;
                    dst[0*WPL+jj]=a0; dst[1*WPL+jj]=a1; dst[2*WPL+jj]=a2; dst[3*WPL+jj]=a3;
                }
            }
        }
    }
    garrive<true>(a.flagsA, 1, g, tid);
    gwait<true>(a.flagsA, 1, tid);

    // ===== Phase B: memory0 -> LDS (64 rows), cos_w^0, state init =====
    {
        const float* kw = a.wp + (size_t)b*WPL;   // t=0 write key
        const int m0 = lane*4;
        float k0=kw[m0], k1=kw[m0+1], k2=kw[m0+2], k3=kw[m0+3];
        float nk = k0*k0 + k1*k1 + k2*k2 + k3*k3;
        #pragma unroll
        for (int off = 32; off; off >>= 1) nk += __shfl_down(nk, off);
        nk = __shfl(nk, 0);
        float snk = sqrtf(nk) + EPSF;
        for (int rr = 0; rr < 8; rr++){
            int j = wvi*8 + rr, n = ns0 + j;
            float4 m4 = ((const float4*)a.memory0)[((size_t)(b*NN+n))*64 + lane];
            *(float4*)&lmem[j][m0] = m4;
            float dw = m4.x*k0 + m4.y*k1 + m4.z*k2 + m4.w*k3;
            float nm = m4.x*m4.x + m4.y*m4.y + m4.z*m4.z + m4.w*m4.w;
            #pragma unroll
            for (int off = 32; off; off >>= 1){ dw += __shfl_down(dw, off); nm += __shfl_down(nm, off); }
            if (lane == 0) cstore(&a.cosw[0*BB*NN + b*NN + n], dw / ((sqrtf(nm)+EPSF)*snk));
        }
        if (tid < SLICE){
            lprec[tid]  = a.prec0[b*NN + ns0 + tid];
            lr_old[tid] = a.read_w0[b*NN + ns0 + tid];
        }
    }
    garrive<false>(a.flagsA, 2, g, tid);
    gwait<false>(a.flagsA, 2, tid);

    // ===== Phase C: redundant write-addr_0 (both teams) + tail(0) =====
    {
        const int half = wvi >> 2, ttid = tid & 255;
        const float* p = a.wp + (size_t)b*WPL;
        float cosx[4], prev[4], wcf[4];
        #pragma unroll
        for (int q = 0; q < 4; q++){
            int i = ttid + q*256;
            cosx[q] = cload(&a.cosw[0*BB*NN + b*NN + i]);
            prev[q] = a.write_w0[b*NN + i];
        }
        addr_team(cosx, prev, p, (half==0)?wgA:wgB,
                  (half==0)?&s16[0]:&s16[8], (half==0)?&s16[4]:&s16[12], ttid, wcf);
        float ag = sigmoidf(p[3*MM+3+KSH]);
        if (half == 0 && ttid >= hbase && ttid < hbase + SLICE){
            int j = ttid - hbase;
            float v = (1.0f - ag)*wcf[qsl];      // alloc == 0 exactly
            lwn[j] = v;
            cstore(&a.wbuf[0*BB*NN + b*NN + ns0 + j], v);
        }
        __syncthreads();
        tail_cos(a, 0, b, g, ns0, lmem, skey, wgB, lwn, nullptr, tid);
        garrive<false>(a.flagsA, 3, g, tid);
        tail_links(a, 0, g, lA, lW, lwn, lr_old, lprec, tid);
        garrive<false>(a.flagsB, 1, g, tid);
        __syncthreads();
        if (tid < SLICE) lw_old[tid] = lwn[tid];
    }

    // ===== Main loop =====
    for (int t = 0; t < TS; t++){
        const int cur = t & 1, nxt = cur ^ 1;
        const int half = wvi >> 2, ttid = tid & 255;
        gwait<false>(a.flagsA, 3 + t, tid);

        // ---- prefetch cos/prev (4 elems per thread per team) ----
        float cosx[4], prev[4];
        const float* addr_p;
        if (half == 0){
            addr_p = a.rp + (size_t)t*BB*RPL + (size_t)b*RPL;
            #pragma unroll
            for (int q = 0; q < 4; q++){
                int i = ttid + q*256;
                cosx[q] = cload(&a.cosr[(size_t)cur*BB*NN + b*NN + i]);
                prev[q] = (t == 0) ? a.read_w0[b*NN + i]
                                   : cload(&a.rdw[(size_t)nxt*BB*NN + b*NN + i]);
            }
        } else {
            int tw = (t < TS-1) ? t+1 : t;   // last step: dummy, discarded
            addr_p = a.wp + (size_t)tw*BB*WPL + (size_t)b*WPL;
            #pragma unroll
            for (int q = 0; q < 4; q++){
                int i = ttid + q*256;
                cosx[q] = cload(&a.cosw[(size_t)nxt*BB*NN + b*NN + i]);
                prev[q] = cload(&a.wbuf[(size_t)cur*BB*NN + b*NN + i]);
            }
        }

        gwait<false>(a.flagsB, 1 + t, tid);   // hoisted: gather issues before addr

        // ---- gather cloads into registers (consumed after addr) ----
        float cv[2] = {0,0}, dv[2] = {0,0};
        {
            int s = tid >> 3, c = tid & 7;
            if (s <= t){
                #pragma unroll
                for (int q = 0; q < 2; q++){
                    int slc = c + q*8;
                    cv[q] = cload(&a.csp[(size_t)cur*GRID*TS + (b*16+slc)*TS + s]);
                    dv[q] = cload(&a.dsp[(size_t)cur*GRID*TS + (b*16+slc)*TS + s]);
                }
            }
        }
        float rdpv = 0.f;
        if (t > 0 && tid < 256){
            int grp = tid >> 4, slc = tid & 15;
            rdpv = cload(&a.rdp[(size_t)nxt*GRID*MM + (size_t)(b*16+slc)*MM + sl*16 + grp]);
        }
        if (tid < SLICE){
            float wsum = 0.f;
            #pragma unroll
            for (int bq = 0; bq < BB; bq++)
                wsum += cload(&a.wbuf[(size_t)cur*BB*NN + bq*NN + ns0 + tid]);
            lprec[tid] = (1.0f - wsum)*lprec[tid] + lw_old[tid];
        }

        // ---- dual-team addressing (4 elems/thread; gather latency hides under it) ----
        float wcf[4];
        addr_team(cosx, prev, addr_p, (half==0)?wgA:wgB,
                  (half==0)?&s16[0]:&s16[8], (half==0)?&s16[4]:&s16[12], ttid, wcf);

        // ---- reduce gathered cs/ds + out_{t-1} ----
        {
            int s = tid >> 3, c = tid & 7;
            float pc = cv[0]+cv[1];
            float pd = dv[0]+dv[1];
            #pragma unroll
            for (int off = 4; off; off >>= 1){ pc += __shfl_down(pc, off); pd += __shfl_down(pd, off); }
            if (c == 0 && s <= t){ scs[s] = pc; sds[s] = pd; }
            if (t > 0 && tid < 256){
                #pragma unroll
                for (int off = 8; off; off >>= 1) rdpv += __shfl_down(rdpv, off);
                if ((tid & 15) == 0) a.out[(size_t)(t-1)*BB*MM + b*MM + sl*16 + (tid>>4)] = rdpv;
            }
        }
        __syncthreads();
        // ---- bwd/fwd with diagonal correction ----
        if (tid < SLICE){
            float bwv = 0.f, fwv = 0.f, qq = 0.f;
            for (int s2 = 0; s2 <= t; s2++){
                float av = lA[s2][tid], wv = lW[s2][tid];
                qq  += av*wv;
                bwv += sds[s2]*av;
                fwv += scs[s2]*wv;
            }
            float corr = lr_old[tid]*qq;
            lbw[tid] = bwv - corr;
            lfw[tid] = fwv - corr;
        }
        __syncthreads();
        // ---- mixes + publishes ----
        if (half == 0){
            float x0 = addr_p[MM+3+KSH], x1 = addr_p[MM+4+KSH], x2 = addr_p[MM+5+KSH];
            float mx = fmaxf(x0, fmaxf(x1, x2));
            float q0 = expf(x0-mx), q1 = expf(x1-mx), q2 = expf(x2-mx);
            float qs = q0+q1+q2;
            float pi0 = q0/qs, pi1 = q1/qs, pi2 = q2/qs;
            if (ttid >= hbase && ttid < hbase + SLICE){
                int j = ttid - hbase;
                float v = pi0*lbw[j] + pi1*wcf[qsl] + pi2*lfw[j];
                lrn[j] = v;
                cstore(&a.rdw[(size_t)cur*BB*NN + b*NN + ns0 + j], v);
            }
        } else if (t < TS-1){
            float ag = sigmoidf(addr_p[3*MM+3+KSH]);
            if (ttid >= hbase && ttid < hbase + SLICE){
                int j = ttid - hbase;
                float v = (1.0f - ag)*wcf[qsl];
                lwn[j] = v;
                cstore(&a.wbuf[(size_t)nxt*BB*NN + b*NN + ns0 + j], v);
            }
        }
        __syncthreads();   // lrn/lwn visible block-wide

        // ---- tail: cos publish -> arriveA; links publish -> arriveB ----
        if (t < TS-1){
            tail_cos(a, t+1, b, g, ns0, lmem, skey, wgB, lwn, lrn, tid);
            garrive<false>(a.flagsA, 4 + t, g, tid);
            tail_links(a, t+1, g, lA, lW, lwn, lrn, lprec, tid);
            garrive<false>(a.flagsB, 2 + t, g, tid);
            __syncthreads();
            if (tid < SLICE){ lr_old[tid] = lrn[tid]; lw_old[tid] = lwn[tid]; }
        } else {
            const int col = tid & 255, rg = tid >> 8;
            float accv = 0.f;
            #pragma unroll 8
            for (int k = 0; k < 32; k++){
                int j = rg*32 + k;
                accv += lrn[j]*lmem[j][col];
            }
            wgB[rg*256 + col] = accv;
            __syncthreads();
            if (tid < 256)
                cstore(&a.rdp[(size_t)1*GRID*MM + g*MM + tid], wgB[tid] + wgB[256+tid]);
            garrive<false>(a.flagsB, 2 + t, g, tid);   // gen TS+1
        }
    }

    // ===== Epilogue: out_31 =====
    gwait<false>(a.flagsB, TS + 1, tid);
    if (tid < 256){
        int grp = tid >> 4, slc = tid & 15;
        float v = cload(&a.rdp[(size_t)1*GRID*MM + (size_t)(b*16+slc)*MM + sl*16 + grp]);
        #pragma unroll
        for (int off = 8; off; off >>= 1) v += __shfl_down(v, off);
        if ((tid & 15) == 0) a.out[(size_t)(TS-1)*BB*MM + b*MM + sl*16 + grp] = v;
    }
}

extern "C" void kernel_launch(void* const* d_in, const int* in_sizes, int n_in,
                              void* d_out, int out_size, void* d_ws, size_t ws_size,
                              hipStream_t stream) {
    KArgs ka;
    ka.ctrl     = (const float*)d_in[0];
    ka.rW       = (const float*)d_in[1];
    ka.rb       = (const float*)d_in[2];
    ka.wW       = (const float*)d_in[3];
    ka.wb       = (const float*)d_in[4];
    ka.memory0  = (const float*)d_in[5];
    // d_in[6] = link0: zeros by construction (rank-t factorization assumes L0=0)
    ka.prec0    = (const float*)d_in[7];
    // d_in[8] = usage0: dead (allocation weights identically zero)
    ka.read_w0  = (const float*)d_in[9];
    ka.write_w0 = (const float*)d_in[10];
    ka.out      = (float*)d_out;

    float* ws = (float*)d_ws;
    size_t off = 0;
    auto alloc = [&](size_t n){ float* p = ws + off; off += n; return p; };
    ka.rp    = alloc((size_t)TS*BB*RPL);       // 33920
    ka.wp    = alloc((size_t)TS*BB*WPL);       // 99200
    ka.cosr  = alloc(2*(size_t)BB*NN);
    ka.cosw  = alloc(2*(size_t)BB*NN);
    ka.wbuf  = alloc(2*(size_t)BB*NN);
    ka.rdw   = alloc(2*(size_t)BB*NN);
    ka.csp   = alloc(2*(size_t)GRID*TS);
    ka.dsp   = alloc(2*(size_t)GRID*TS);
    ka.rdp   = alloc(2*(size_t)GRID*MM);       // coalesced layout
    unsigned* ubase = (unsigned*)(ws + off);
    ka.flagsA = ubase;
    ka.flagsB = ubase + GRID*16;
    size_t bar_bytes = (2*GRID*16) * sizeof(unsigned);

    hipMemsetAsync((void*)ubase, 0, bar_bytes, stream);
    void* params[] = { &ka };
    hipLaunchCooperativeKernel((const void*)kfull, dim3(GRID), dim3(TPB), params, 0, stream);
}

// Round 15
// 332.890 us; speedup vs baseline: 1.1416x; 1.1416x over previous
//
#include <hip/hip_runtime.h>

#define GRID 128
#define TPB 256
#define SLICE 32          // memory rows per block
#define BB 4
#define DD 256
#define NN 1024
#define MM 256
#define KSH 3
#define RPL 265   // M+K+6
#define WPL 775   // 3M+K+4
#define TS 32
#define EPSF 1e-12f

struct KArgs {
    const float *ctrl, *rW, *rb, *wW, *wb;
    const float *memory0, *prec0, *read_w0, *write_w0;
    float *out;
    float *rp, *wp;                        // params: cached (published once via fenced barrier)
    float *cosr, *cosw, *wbuf, *rdw;       // [2][B][N] parity double-buffered, LLC-coherent access
    float *csp, *dsp;                      // [2][GRID][TS]
    float *rdp;                            // [2][GRID][MM] coalesced
    unsigned *flagsA, *flagsB;
};

// LLC-coherent scalar access (sc0 sc1): bypasses non-coherent L1/L2, no fences needed.
__device__ __forceinline__ float cload(const float* p){
    return __hip_atomic_load(p, __ATOMIC_RELAXED, __HIP_MEMORY_SCOPE_SYSTEM);
}
__device__ __forceinline__ void cstore(float* p, float v){
    __hip_atomic_store(p, v, __ATOMIC_RELAXED, __HIP_MEMORY_SCOPE_SYSTEM);
}

__device__ __forceinline__ float softplusf(float x){
    return fmaxf(x, 0.0f) + log1pf(expf(-fabsf(x)));
}
__device__ __forceinline__ float sigmoidf(float x){
    return 1.0f / (1.0f + expf(-x));
}

// arrive: publish own flag (syncthreads drains vmcnt -> cstores LLC-visible first)
template <bool FENCE>
__device__ __forceinline__ void garrive(unsigned* flags, unsigned gen, int g, int tid){
    __syncthreads();
    if (tid == 0){
        if (FENCE) __builtin_amdgcn_fence(__ATOMIC_RELEASE, "agent");
        __hip_atomic_store(&flags[g*16], gen, __ATOMIC_RELAXED, __HIP_MEMORY_SCOPE_SYSTEM);
    }
}
// global wait: poll all 128 flags (2/lane)
template <bool FENCE>
__device__ __forceinline__ void gwait(unsigned* flags, unsigned gen, int tid){
    if (tid < 64){
        while (1){
            unsigned f0 = __hip_atomic_load(&flags[tid*16], __ATOMIC_RELAXED, __HIP_MEMORY_SCOPE_SYSTEM);
            unsigned f1 = __hip_atomic_load(&flags[(tid+64)*16], __ATOMIC_RELAXED, __HIP_MEMORY_SCOPE_SYSTEM);
            if (__all(f0 >= gen && f1 >= gen)) break;
            __builtin_amdgcn_s_sleep(1);
        }
    }
    __syncthreads();
    if (FENCE) __builtin_amdgcn_fence(__ATOMIC_ACQUIRE, "agent");
    asm volatile("" ::: "memory");
}
// batch-local wait: poll only own batch's 32 flags. Straggler set 128 -> 32.
// Valid because everything gated by flagsA is batch-local (cos/rdw/wbuf-prev);
// cross-batch data (wbuf wsum, csp/dsp, rdp) is gated by the GLOBAL flagsB wait,
// which trails a whole tail-phase behind (pipelined, rarely blocking).
__device__ __forceinline__ void gwaitA(unsigned* flags, unsigned gen, int b, int tid){
    if (tid < 64){
        int idx = b*32 + (tid & 31);
        while (1){
            unsigned f0 = __hip_atomic_load(&flags[idx*16], __ATOMIC_RELAXED, __HIP_MEMORY_SCOPE_SYSTEM);
            if (__all(f0 >= gen)) break;
            __builtin_amdgcn_s_sleep(1);
        }
    }
    __syncthreads();
    asm volatile("" ::: "memory");
}

// full-block reductions (prologue addressing only)
__device__ __forceinline__ float blk_sum(float v, float* s4, int tid){
    #pragma unroll
    for (int off = 32; off; off >>= 1) v += __shfl_down(v, off);
    if ((tid & 63) == 0) s4[tid >> 6] = v;
    __syncthreads();
    float r = s4[0] + s4[1] + s4[2] + s4[3];
    __syncthreads();
    return r;
}

// half-block (128-thread) reductions — both halves execute the same call sites,
// same __syncthreads counts, distinct slot pairs.
__device__ __forceinline__ float half_sum(float v, float* slots, int htid){
    #pragma unroll
    for (int off = 32; off; off >>= 1) v += __shfl_down(v, off);
    if ((htid & 63) == 0) slots[htid >> 6] = v;
    __syncthreads();
    float r = slots[0] + slots[1];
    __syncthreads();
    return r;
}

// full-block addressing (prologue t=0 write-addr only); 4 elems/thread
__device__ __forceinline__ void addr_core2(const float cosx[4], const float prev[4],
                                           const float* __restrict__ p,
                                           float* s4, float* wg, int tid,
                                           float out_wc[4]){
    float beta_p  = softplusf(p[MM]);
    float g       = sigmoidf(p[MM+1]);
    float s0r = p[MM+2], s1r = p[MM+3], s2r = p[MM+4];
    float smx = fmaxf(s0r, fmaxf(s1r, s2r));
    float e0 = expf(s0r-smx), e1 = expf(s1r-smx), e2 = expf(s2r-smx);
    float sden = e0+e1+e2;
    float s0 = e0/sden, s1 = e1/sden, s2 = e2/sden;
    float gamma_p = 1.0f + softplusf(p[MM+2+KSH]);
    // bmax := beta_p (>= max beta_p*cos, shift-invariant, no reduction needed)
    float ev[4]; float ls = 0.0f;
    #pragma unroll
    for (int q = 0; q < 4; q++){ ev[q] = expf(beta_p*cosx[q] - beta_p); ls += ev[q]; }
    float bs = blk_sum(ls, s4, tid);
    float invb = 1.0f / bs;
    #pragma unroll
    for (int q = 0; q < 4; q++){
        int i = tid + q*256;
        wg[i] = g*(ev[q]*invb) + (1.0f-g)*prev[q];
    }
    __syncthreads();
    float wt[4]; float lps = 0.0f;
    #pragma unroll
    for (int q = 0; q < 4; q++){
        int i = tid + q*256;
        float sh = s0*wg[(i+1)&(NN-1)] + s1*wg[i] + s2*wg[(i-1)&(NN-1)];
        wt[q] = exp2f(gamma_p * log2f(sh + EPSF));
        lps += wt[q];
    }
    float ts = blk_sum(lps, s4, tid);
    float inv = 1.0f / (ts + EPSF);
    #pragma unroll
    for (int q = 0; q < 4; q++) out_wc[q] = wt[q] * inv;
    __syncthreads();
}

// half-block addressing: 8 elems/thread over full N=1024, no max reduction
__device__ __forceinline__ void addr_half(const float cosx[8], const float prev[8],
                                          const float* __restrict__ p,
                                          float* swg, float* slots,
                                          int htid, float out_wc[8]){
    float beta_p  = softplusf(p[MM]);
    float g       = sigmoidf(p[MM+1]);
    float s0r = p[MM+2], s1r = p[MM+3], s2r = p[MM+4];
    float smx = fmaxf(s0r, fmaxf(s1r, s2r));
    float e0 = expf(s0r-smx), e1 = expf(s1r-smx), e2 = expf(s2r-smx);
    float sden = e0+e1+e2;
    float s0 = e0/sden, s1 = e1/sden, s2 = e2/sden;
    float gamma_p = 1.0f + softplusf(p[MM+2+KSH]);

    float ev[8]; float ls = 0.0f;
    #pragma unroll
    for (int q = 0; q < 8; q++){ ev[q] = expf(beta_p*cosx[q] - beta_p); ls += ev[q]; }
    float bs = half_sum(ls, slots, htid);
    float invb = 1.0f / bs;
    #pragma unroll
    for (int q = 0; q < 8; q++){
        int i = htid + q*128;
        swg[i] = g*(ev[q]*invb) + (1.0f-g)*prev[q];
    }
    __syncthreads();
    float wt[8]; float lps = 0.0f;
    #pragma unroll
    for (int q = 0; q < 8; q++){
        int i = htid + q*128;
        float sh = s0*swg[(i+1)&(NN-1)] + s1*swg[i] + s2*swg[(i-1)&(NN-1)];
        wt[q] = exp2f(gamma_p * log2f(sh + EPSF));
        lps += wt[q];
    }
    float ts2 = half_sum(lps, slots, htid);
    float inv = 1.0f / (ts2 + EPSF);
    #pragma unroll
    for (int q = 0; q < 8; q++) out_wc[q] = wt[q] * inv;
    __syncthreads();
}

// Tail work for step `tnext`: reads_{tnext-1} (if rdvec), mem update with w_{tnext}
// (lwn), cosr_{tnext}, cosw_{tnext+1} (r10 version — the measured-best tail).
__device__ __forceinline__ void tail_cos(const KArgs& a, int tnext, int b, int g, int ns0,
        float (*lmem)[MM], float (*skey)[MM],
        const float* lwn, const float* rdvec, int tid){
    if (rdvec){
        float accv = 0.f;
        #pragma unroll 8
        for (int j = 0; j < SLICE; j++) accv += rdvec[j]*lmem[j][tid];
        cstore(&a.rdp[(size_t)((tnext-1)&1)*GRID*MM + g*MM + tid], accv);
    }
    const float* kr = a.rp + (size_t)tnext*BB*RPL + (size_t)b*RPL;
    const bool hw = (tnext+1 <= TS-1);
    const float* kwp = a.wp + (size_t)(hw ? tnext+1 : tnext)*BB*WPL + (size_t)b*WPL;
    skey[0][tid] = kr[tid];
    skey[1][tid] = kwp[tid];
    __syncthreads();   // rdvec reads + skey staged before lmem overwrite
    {
        const float* pw = a.wp + (size_t)tnext*BB*WPL + (size_t)b*WPL;
        float e = pw[MM+3+KSH + tid];       // pre-sigmoided erase
        float d = pw[2*MM+3+KSH + tid];
        #pragma unroll 8
        for (int j = 0; j < SLICE; j++){
            float w = lwn[j];
            lmem[j][tid] = lmem[j][tid]*(1.0f - w*e) + w*d;
        }
    }
    __syncthreads();
    {
        int j = tid >> 3, c = tid & 7;
        float dr=0.f, dw=0.f, nm=0.f, nr=0.f, nk=0.f;
        #pragma unroll
        for (int m = 0; m < 8; m++){
            int col = c*4 + m*32;
            float4 mv = *(const float4*)&lmem[j][col];
            float4 rv = *(const float4*)&skey[0][col];
            float4 wv = *(const float4*)&skey[1][col];
            dr += mv.x*rv.x + mv.y*rv.y + mv.z*rv.z + mv.w*rv.w;
            dw += mv.x*wv.x + mv.y*wv.y + mv.z*wv.z + mv.w*wv.w;
            nm += mv.x*mv.x + mv.y*mv.y + mv.z*mv.z + mv.w*mv.w;
            nr += rv.x*rv.x + rv.y*rv.y + rv.z*rv.z + rv.w*rv.w;
            nk += wv.x*wv.x + wv.y*wv.y + wv.z*wv.z + wv.w*wv.w;
        }
        #pragma unroll
        for (int off = 4; off; off >>= 1){
            dr += __shfl_down(dr, off); dw += __shfl_down(dw, off);
            nm += __shfl_down(nm, off); nr += __shfl_down(nr, off);
            nk += __shfl_down(nk, off);
        }
        if (c == 0){
            float sn = sqrtf(nm) + EPSF;
            int n = ns0 + j;
            cstore(&a.cosr[(size_t)(tnext&1)*BB*NN + b*NN + n], dr/(sn*(sqrtf(nr)+EPSF)));
            if (hw) cstore(&a.cosw[(size_t)((tnext+1)&1)*BB*NN + b*NN + n], dw/(sn*(sqrtf(nk)+EPSF)));
        }
    }
}

// tail part 2: A/W scale+append, cs/ds partials publish (r10 version).
__device__ __forceinline__ void tail_links(const KArgs& a, int tnext, int g,
        float (*lA)[SLICE], float (*lW)[SLICE],
        const float* lwn, const float* rvec, const float* lprec, int tid){
    for (int p2 = tid; p2 < tnext*SLICE; p2 += TPB){
        int s = p2 >> 5, jj = p2 & 31;
        lA[s][jj] *= (1.0f - lwn[jj]);
    }
    __syncthreads();
    if (tid < SLICE){ lA[tnext][tid] = lprec[tid]; lW[tnext][tid] = lwn[tid]; }
    __syncthreads();
    int s = tid >> 3, c = tid & 7;
    if (s <= tnext){
        float pc = 0.f, pd = 0.f;
        #pragma unroll
        for (int q = 0; q < 4; q++){
            int jj = c*4 + q;
            float r = rvec[jj];
            pc += r*lA[s][jj];
            pd += r*lW[s][jj];
        }
        #pragma unroll
        for (int off = 4; off; off >>= 1){ pc += __shfl_down(pc, off); pd += __shfl_down(pd, off); }
        if (c == 0){
            cstore(&a.csp[(size_t)(tnext&1)*GRID*TS + g*TS + s], pc);
            cstore(&a.dsp[(size_t)(tnext&1)*GRID*TS + g*TS + s], pd);
        }
    }
}

__global__ void __launch_bounds__(TPB) kfull(KArgs a){
    const int g   = blockIdx.x;
    const int tid = threadIdx.x;
    const int wvi = tid >> 6, lane = tid & 63;
    const int b   = g >> 5;             // batch
    const int sl  = g & 31;             // slice index within batch
    const int ns0 = sl * SLICE;         // first row of slice
    const int sq    = sl >> 3;          // full-block layout slice q
    const int sbase = (sl & 7) * 32;    // full-block layout slice tid base
    const int hbase = ns0 & 127;        // half layout: slice tid base
    const int qsl   = ns0 >> 7;         // half layout: slice q

    __shared__ __align__(16) float lmem[SLICE][MM];   // 32 KB memory slice
    __shared__ __align__(16) float skey[2][MM];
    __shared__ __align__(16) float lA[TS][SLICE];
    __shared__ __align__(16) float lW[TS][SLICE];
    __shared__ float wgA[NN], wgB[NN];
    __shared__ float s8[8];
    __shared__ float scs[TS], sds[TS];
    __shared__ float lprec[SLICE], lr_old[SLICE], lw_old[SLICE];
    __shared__ float lrn[SLICE], lwn[SLICE], lbw[SLICE], lfw[SLICE];

    // ===== Phase A: projections (cached stores; published by fenced barrier) =====
    {
        const int tt = g >> 2;
        for (int o = tid; o < BB*DD; o += TPB) wgA[o] = a.ctrl[(size_t)tt*BB*DD + o];
        __syncthreads();
        for (int half = 0; half < 2; half++){
            int jc = (g & 3) + half*4;
            int j = jc*130 + tid;
            if (tid < 130 && j < RPL + WPL){
                const float* wrow; float bias; int isw, jj;
                if (j < RPL){ jj = j;       wrow = a.rW + (size_t)jj*DD; bias = a.rb[jj]; isw = 0; }
                else        { jj = j - RPL; wrow = a.wW + (size_t)jj*DD; bias = a.wb[jj]; isw = 1; }
                const float4* w4 = (const float4*)wrow;
                float a0 = bias, a1 = bias, a2 = bias, a3 = bias;
                for (int d = 0; d < DD/4; d++){
                    float4 wv = w4[d];
                    float4 c0 = *(const float4*)&wgA[0*DD + d*4];
                    float4 c1 = *(const float4*)&wgA[1*DD + d*4];
                    float4 c2 = *(const float4*)&wgA[2*DD + d*4];
                    float4 c3 = *(const float4*)&wgA[3*DD + d*4];
                    a0 += wv.x*c0.x + wv.y*c0.y + wv.z*c0.z + wv.w*c0.w;
                    a1 += wv.x*c1.x + wv.y*c1.y + wv.z*c1.z + wv.w*c1.w;
                    a2 += wv.x*c2.x + wv.y*c2.y + wv.z*c2.z + wv.w*c2.w;
                    a3 += wv.x*c3.x + wv.y*c3.y + wv.z*c3.z + wv.w*c3.w;
                }
                if (isw && jj >= MM+3+KSH && jj < 2*MM+3+KSH){  // erase -> sigmoid once
                    a0 = sigmoidf(a0); a1 = sigmoidf(a1); a2 = sigmoidf(a2); a3 = sigmoidf(a3);
                }
                if (!isw){
                    float* dst = a.rp + (size_t)tt*BB*RPL;
                    dst[0*RPL+jj]=a0; dst[1*RPL+jj]=a1; dst[2*RPL+jj]=a2; dst[3*RPL+jj]=a3;
                } else {
                    float* dst = a.wp + (size_t)tt*BB*WPL;
                    dst[0*WPL+jj]=a0; dst[1*WPL+jj]=a1; dst[2*WPL+jj]=a2; dst[3*WPL+jj]=a3;
                }
            }
        }
    }
    garrive<true>(a.flagsA, 1, g, tid);
    gwait<true>(a.flagsA, 1, tid);

    // ===== Phase B: memory0 -> LDS, cos_w^0 -> cosw[0], state init =====
    {
        const float* kw = a.wp + (size_t)b*WPL;   // t=0 write key
        const int m0 = lane*4;
        float k0=kw[m0], k1=kw[m0+1], k2=kw[m0+2], k3=kw[m0+3];
        float nk = k0*k0 + k1*k1 + k2*k2 + k3*k3;
        #pragma unroll
        for (int off = 32; off; off >>= 1) nk += __shfl_down(nk, off);
        nk = __shfl(nk, 0);
        float snk = sqrtf(nk) + EPSF;
        for (int rr = 0; rr < 8; rr++){
            int j = wvi*8 + rr, n = ns0 + j;
            float4 m4 = ((const float4*)a.memory0)[((size_t)(b*NN+n))*64 + lane];
            *(float4*)&lmem[j][m0] = m4;
            float dw = m4.x*k0 + m4.y*k1 + m4.z*k2 + m4.w*k3;
            float nm = m4.x*m4.x + m4.y*m4.y + m4.z*m4.z + m4.w*m4.w;
            #pragma unroll
            for (int off = 32; off; off >>= 1){ dw += __shfl_down(dw, off); nm += __shfl_down(nm, off); }
            if (lane == 0) cstore(&a.cosw[0*BB*NN + b*NN + n], dw / ((sqrtf(nm)+EPSF)*snk));
        }
        if (tid < SLICE){
            lprec[tid]  = a.prec0[b*NN + ns0 + tid];
            lr_old[tid] = a.read_w0[b*NN + ns0 + tid];
        }
    }
    garrive<false>(a.flagsA, 2, g, tid);
    gwait<false>(a.flagsA, 2, tid);

    // ===== Phase C: redundant write-addr_0 + tail(0) =====
    {
        const float* p = a.wp + (size_t)b*WPL;
        float cosx[4], prev[4], wcf[4];
        #pragma unroll
        for (int q = 0; q < 4; q++){
            int i = tid + q*256;
            cosx[q] = cload(&a.cosw[0*BB*NN + b*NN + i]);
            prev[q] = a.write_w0[b*NN + i];
        }
        addr_core2(cosx, prev, p, s8, wgA, tid, wcf);
        float ag = sigmoidf(p[3*MM+3+KSH]);
        if (tid >= sbase && tid < sbase+32){
            int j = tid - sbase;
            float v = (1.0f - ag)*wcf[sq];      // alloc == 0 exactly
            lwn[j] = v;
            cstore(&a.wbuf[0*BB*NN + b*NN + ns0 + j], v);
        }
        __syncthreads();
        tail_cos(a, 0, b, g, ns0, lmem, skey, lwn, nullptr, tid);
        garrive<false>(a.flagsA, 3, g, tid);
        tail_links(a, 0, g, lA, lW, lwn, lr_old, lprec, tid);
        garrive<false>(a.flagsB, 1, g, tid);
        __syncthreads();
        if (tid < SLICE) lw_old[tid] = lwn[tid];
    }

    // ===== Main loop: batch-local waitA + global pipelined waitB =====
    for (int t = 0; t < TS; t++){
        const int cur = t & 1, nxt = cur ^ 1;
        const int half = wvi >> 1, htid = tid & 127;
        gwaitA(a.flagsA, 3 + t, b, tid);   // BATCH-LOCAL: straggler set 128 -> 32

        // ---- prefetch (issue all cos/prev cloads) ----
        float cosx[8], prev[8];
        const float* addr_p;
        if (half == 0){
            addr_p = a.rp + (size_t)t*BB*RPL + (size_t)b*RPL;
            #pragma unroll
            for (int q = 0; q < 8; q++){
                int i = htid + q*128;
                cosx[q] = cload(&a.cosr[(size_t)cur*BB*NN + b*NN + i]);
                prev[q] = (t == 0) ? a.read_w0[b*NN + i]
                                   : cload(&a.rdw[(size_t)nxt*BB*NN + b*NN + i]);
            }
        } else {
            int tw = (t < TS-1) ? t+1 : t;   // last step: dummy, discarded
            addr_p = a.wp + (size_t)tw*BB*WPL + (size_t)b*WPL;
            #pragma unroll
            for (int q = 0; q < 8; q++){
                int i = htid + q*128;
                cosx[q] = cload(&a.cosw[(size_t)nxt*BB*NN + b*NN + i]);
                prev[q] = cload(&a.wbuf[(size_t)cur*BB*NN + b*NN + i]);
            }
        }

        // ---- GLOBAL waitB (pipelined one tail-phase behind; gates cross-batch
        // wbuf wsum + csp/dsp + rdp) ----
        gwait<false>(a.flagsB, 1 + t, tid);

        // ---- gather cloads into registers (consumed after addr) ----
        float cv[4] = {0,0,0,0}, dv[4] = {0,0,0,0};
        {
            int s = tid >> 3, c = tid & 7;
            if (s <= t){
                #pragma unroll
                for (int q = 0; q < 4; q++){
                    int slc = c + q*8;
                    cv[q] = cload(&a.csp[(size_t)cur*GRID*TS + (b*32+slc)*TS + s]);
                    dv[q] = cload(&a.dsp[(size_t)cur*GRID*TS + (b*32+slc)*TS + s]);
                }
            }
        }
        float rdpv = 0.f;
        if (t > 0)
            rdpv = cload(&a.rdp[(size_t)nxt*GRID*MM + (size_t)(b*32+(tid&31))*MM + sl*8 + (tid>>5)]);
        if (tid < SLICE){
            float wsum = 0.f;
            #pragma unroll
            for (int bq = 0; bq < BB; bq++)
                wsum += cload(&a.wbuf[(size_t)cur*BB*NN + bq*NN + ns0 + tid]);
            lprec[tid] = (1.0f - wsum)*lprec[tid] + lw_old[tid];
        }

        // ---- dual-half addressing (gather latency hides under this) ----
        float wcf[8];
        addr_half(cosx, prev, addr_p,
                  (half == 0) ? wgA : wgB,
                  (half == 0) ? &s8[0] : &s8[2],
                  htid, wcf);

        // ---- reduce gathered cs/ds + out_{t-1} ----
        {
            int s = tid >> 3, c = tid & 7;
            float pc = cv[0]+cv[1]+cv[2]+cv[3];
            float pd = dv[0]+dv[1]+dv[2]+dv[3];
            #pragma unroll
            for (int off = 4; off; off >>= 1){ pc += __shfl_down(pc, off); pd += __shfl_down(pd, off); }
            if (c == 0 && s <= t){ scs[s] = pc; sds[s] = pd; }
            if (t > 0){
                #pragma unroll
                for (int off = 16; off; off >>= 1) rdpv += __shfl_down(rdpv, off);
                if ((tid & 31) == 0) a.out[(size_t)(t-1)*BB*MM + b*MM + sl*8 + (tid>>5)] = rdpv;
            }
        }
        __syncthreads();
        // ---- bwd/fwd with diagonal correction ----
        if (tid < SLICE){
            float bwv = 0.f, fwv = 0.f, qq = 0.f;
            for (int s2 = 0; s2 <= t; s2++){
                float av = lA[s2][tid], wv = lW[s2][tid];
                qq  += av*wv;
                bwv += sds[s2]*av;
                fwv += scs[s2]*wv;
            }
            float corr = lr_old[tid]*qq;
            lbw[tid] = bwv - corr;
            lfw[tid] = fwv - corr;
        }
        __syncthreads();
        // ---- mixes + publishes ----
        if (half == 0){
            float x0 = addr_p[MM+3+KSH], x1 = addr_p[MM+4+KSH], x2 = addr_p[MM+5+KSH];
            float mx = fmaxf(x0, fmaxf(x1, x2));
            float q0 = expf(x0-mx), q1 = expf(x1-mx), q2 = expf(x2-mx);
            float qs = q0+q1+q2;
            float pi0 = q0/qs, pi1 = q1/qs, pi2 = q2/qs;
            if (htid >= hbase && htid < hbase + 32){
                int j = htid - hbase;
                float v = pi0*lbw[j] + pi1*wcf[qsl] + pi2*lfw[j];
                lrn[j] = v;
                cstore(&a.rdw[(size_t)cur*BB*NN + b*NN + ns0 + j], v);
            }
        } else if (t < TS-1){
            float ag = sigmoidf(addr_p[3*MM+3+KSH]);
            if (htid >= hbase && htid < hbase + 32){
                int j = htid - hbase;
                float v = (1.0f - ag)*wcf[qsl];
                lwn[j] = v;
                cstore(&a.wbuf[(size_t)nxt*BB*NN + b*NN + ns0 + j], v);
            }
        }
        __syncthreads();   // lrn/lwn visible block-wide

        // ---- tail: cos publish -> arriveA; links publish -> arriveB ----
        if (t < TS-1){
            tail_cos(a, t+1, b, g, ns0, lmem, skey, lwn, lrn, tid);
            garrive<false>(a.flagsA, 4 + t, g, tid);
            tail_links(a, t+1, g, lA, lW, lwn, lrn, lprec, tid);
            garrive<false>(a.flagsB, 2 + t, g, tid);
            __syncthreads();
            if (tid < SLICE){ lr_old[tid] = lrn[tid]; lw_old[tid] = lwn[tid]; }
        } else {
            float accv = 0.f;
            #pragma unroll 8
            for (int j = 0; j < SLICE; j++) accv += lrn[j]*lmem[j][tid];
            cstore(&a.rdp[(size_t)1*GRID*MM + g*MM + tid], accv);
            garrive<false>(a.flagsB, 2 + t, g, tid);   // gen TS+1
        }
    }

    // ===== Epilogue: out_31 =====
    gwait<false>(a.flagsB, TS + 1, tid);
    {
        float v = cload(&a.rdp[(size_t)1*GRID*MM + (size_t)(b*32+(tid&31))*MM + sl*8 + (tid>>5)]);
        #pragma unroll
        for (int off = 16; off; off >>= 1) v += __shfl_down(v, off);
        if ((tid & 31) == 0) a.out[(size_t)(TS-1)*BB*MM + b*MM + sl*8 + (tid>>5)] = v;
    }
}

extern "C" void kernel_launch(void* const* d_in, const int* in_sizes, int n_in,
                              void* d_out, int out_size, void* d_ws, size_t ws_size,
                              hipStream_t stream) {
    KArgs ka;
    ka.ctrl     = (const float*)d_in[0];
    ka.rW       = (const float*)d_in[1];
    ka.rb       = (const float*)d_in[2];
    ka.wW       = (const float*)d_in[3];
    ka.wb       = (const float*)d_in[4];
    ka.memory0  = (const float*)d_in[5];
    // d_in[6] = link0: zeros by construction (rank-t factorization assumes L0=0)
    ka.prec0    = (const float*)d_in[7];
    // d_in[8] = usage0: dead (allocation weights identically zero)
    ka.read_w0  = (const float*)d_in[9];
    ka.write_w0 = (const float*)d_in[10];
    ka.out      = (float*)d_out;

    float* ws = (float*)d_ws;
    size_t off = 0;
    auto alloc = [&](size_t n){ float* p = ws + off; off += n; return p; };
    ka.rp    = alloc((size_t)TS*BB*RPL);       // 33920
    ka.wp    = alloc((size_t)TS*BB*WPL);       // 99200
    ka.cosr  = alloc(2*(size_t)BB*NN);
    ka.cosw  = alloc(2*(size_t)BB*NN);
    ka.wbuf  = alloc(2*(size_t)BB*NN);
    ka.rdw   = alloc(2*(size_t)BB*NN);
    ka.csp   = alloc(2*(size_t)GRID*TS);
    ka.dsp   = alloc(2*(size_t)GRID*TS);
    ka.rdp   = alloc(2*(size_t)GRID*MM);       // 65536, coalesced layout
    unsigned* ubase = (unsigned*)(ws + off);
    ka.flagsA = ubase;
    ka.flagsB = ubase + GRID*16;
    size_t bar_bytes = (2*GRID*16) * sizeof(unsigned);

    hipMemsetAsync((void*)ubase, 0, bar_bytes, stream);
    void* params[] = { &ka };
    hipLaunchCooperativeKernel((const void*)kfull, dim3(GRID), dim3(TPB), params, 0, stream);
}